// Round 1
// 369.391 us; speedup vs baseline: 1.3855x; 1.3855x over previous
//
#include <hip/hip_runtime.h>

// Problem dims
#define B_   256
#define N_   16000
#define C_   32
#define K_   64
#define T_   124
#define NJ   125      // 128-sample half-window block sums, j = 0..124
#define HID_ 50
#define OUT_ 10
#define TB_  1024     // snnB block size (r15: 256 -> 1024 for latency hiding)

typedef unsigned int u32;

// Exact single f32 ops (prevent fma contraction / reassociation).
__device__ __forceinline__ float fadd(float a, float b) { return __fadd_rn(a, b); }
__device__ __forceinline__ float fmul(float a, float b) { return __fmul_rn(a, b); }
__device__ __forceinline__ float fsub(float a, float b) { return __fsub_rn(a, b); }
// Compile-time float4 component select (folds after unroll).
__device__ __forceinline__ float f4c(const float4& v, int i) {
    switch (i) { case 0: return v.x; case 1: return v.y; case 2: return v.z; default: return v.w; }
}

// ---------------------------------------------------------------------------
// Kernel A: conv (SAME pad_lo=31, correlation, sequential-k f32 FMA) + relu +
// numpy-pairwise 128-block sums -> Sg[b][c][j] (f32 global scratch).
//
// ROUND-15: amortize tap reads over all 4 pp sub-tiles. The 4 uniform tap
// ds_read_b128 per q do not depend on pp, so pp moves INSIDE the q loop:
// per q-iter = 4 tap reads + 4 audio reads + 256 FMAs (was 5 reads / 64
// FMAs). LDS b128 traffic per block 2720 -> 1088; Tp v_movs amortized 4x;
// FMA fraction of VALU 64/85 -> 256/284. Accumulator y[4][4][4] = 64 VGPR,
// all indices compile-time (no scratch); q loop stays #pragma unroll 1 so
// the scheduled live set is one iteration (~130-160 VGPR < 256 cap).
// Per-output accumulation order (k ascending via q,e) unchanged: bit-exact.
//
// Grid (B,16): one 1024-sample segment per block; wave w, group G in {0,1}
// owns channels w*8 + G*4 + {0..3}. LDS 29.7 KB.
// ---------------------------------------------------------------------------
__global__ __launch_bounds__(256, 2) void convA(const float* __restrict__ audio,
                                                const float* __restrict__ gt,
                                                float* __restrict__ Sg) {
    __shared__ __align__(16) float abuf[1152];        //  4,608 B
    __shared__ __align__(16) float kLDS[C_ * K_];     //  8,192 B
    __shared__ __align__(16) float ybuf[4][4][264];   // 16,896 B [wave][ch][2blk*132]

    const int b = blockIdx.x, g = blockIdx.y;
    const int tid = threadIdx.x, w = tid >> 6, lane = tid & 63;
    const float* arow = audio + (size_t)b * N_;

    const int origin = (g << 10) - 32;
    for (int i = tid; i < 1152; i += 256) {
        int gi = origin + i;
        abuf[i] = (gi >= 0 && gi < N_) ? arow[gi] : 0.0f;
    }
    for (int i = tid; i < C_ * K_; i += 256) kLDS[i] = gt[i];
    __syncthreads();

    const int La = lane << 2;

    for (int G = 0; G < 2; ++G) {
        const float* kgrp = &kLDS[((w << 3) + (G << 2)) << 6];  // ch base row

        float y[4][4][4];   // [pp][ch][d] — 64 accumulators, compile-time idx
#pragma unroll
        for (int pp = 0; pp < 4; ++pp)
#pragma unroll
            for (int ch = 0; ch < 4; ++ch)
#pragma unroll
                for (int d = 0; d < 4; ++d) y[pp][ch][d] = 0.0f;

        float4 Tp[4];

        // ---- q = 0 peel: kb = e-1-d, only kb>=0 terms (all from Tc)
        {
            float4 Tc[4];
#pragma unroll
            for (int ch = 0; ch < 4; ++ch)
                Tc[ch] = *(const float4*)(kgrp + (ch << 6));
#pragma unroll
            for (int pp = 0; pp < 4; ++pp) {
                float4 A4 = *(const float4*)(abuf + (pp << 8) + La);
#pragma unroll
                for (int e = 0; e < 4; ++e) {
                    const float a = f4c(A4, e);
#pragma unroll
                    for (int ch = 0; ch < 4; ++ch)
#pragma unroll
                        for (int d = 0; d < 4; ++d) {
                            const int kb = e - 1 - d;          // compile-time
                            if (kb >= 0)
                                y[pp][ch][d] = fmaf(a, f4c(Tc[ch], kb), y[pp][ch][d]);
                        }
                }
            }
#pragma unroll
            for (int ch = 0; ch < 4; ++ch) Tp[ch] = Tc[ch];
        }

        // ---- q = 1..15: boundary-free, NOT unrolled (live set = 1 iter)
#pragma unroll 1
        for (int q = 1; q < 16; ++q) {
            float4 Tc[4];
#pragma unroll
            for (int ch = 0; ch < 4; ++ch)
                Tc[ch] = *(const float4*)(kgrp + (ch << 6) + (q << 2));
#pragma unroll
            for (int pp = 0; pp < 4; ++pp) {
                float4 A4 = *(const float4*)(abuf + (pp << 8) + La + (q << 2));
#pragma unroll
                for (int e = 0; e < 4; ++e) {
                    const float a = f4c(A4, e);
#pragma unroll
                    for (int ch = 0; ch < 4; ++ch)
#pragma unroll
                        for (int d = 0; d < 4; ++d) {
                            const int ts = e - 1 - d;          // compile-time
                            const float tap = (ts >= 0) ? f4c(Tc[ch], ts)
                                                        : f4c(Tp[ch], 4 + ts);
                            y[pp][ch][d] = fmaf(a, tap, y[pp][ch][d]);
                        }
                }
            }
#pragma unroll
            for (int ch = 0; ch < 4; ++ch) Tp[ch] = Tc[ch];
        }

        // ---- q = 16 peel: only ts<0 (Tp) terms
        {
#pragma unroll
            for (int pp = 0; pp < 4; ++pp) {
                float4 A4 = *(const float4*)(abuf + (pp << 8) + La + 64);
#pragma unroll
                for (int e = 0; e < 4; ++e) {
                    const float a = f4c(A4, e);
#pragma unroll
                    for (int ch = 0; ch < 4; ++ch)
#pragma unroll
                        for (int d = 0; d < 4; ++d) {
                            const int ts = e - 1 - d;          // compile-time
                            if (ts < 0)
                                y[pp][ch][d] = fmaf(a, f4c(Tp[ch], 4 + ts), y[pp][ch][d]);
                        }
                }
            }
        }

        // ---- epilogue per pp (unchanged math; pp unrolled => y idx static)
#pragma unroll
        for (int pp = 0; pp < 4; ++pp) {
#pragma unroll
            for (int ch = 0; ch < 4; ++ch) {
                float4 z;
                z.x = fmaxf(y[pp][ch][0], 0.0f); z.y = fmaxf(y[pp][ch][1], 0.0f);
                z.z = fmaxf(y[pp][ch][2], 0.0f); z.w = fmaxf(y[pp][ch][3], 0.0f);
                *(float4*)(&ybuf[w][ch][((lane >> 5) * 132) + ((lane & 31) << 2)]) = z;
            }
            // numpy pairwise-128: 64 lanes = 4ch x 2blk x 8slots.
            {
                const int ch2 = lane >> 4, blk = (lane >> 3) & 1, j = lane & 7;
                const float* yb = &ybuf[w][ch2][blk * 132 + j];
                float r = yb[0];
#pragma unroll
                for (int m = 1; m < 16; ++m) r = fadd(r, yb[m << 3]);
                float v = fadd(r, __shfl_xor(r, 1));
                v = fadd(v, __shfl_xor(v, 2));
                v = fadd(v, __shfl_xor(v, 4));
                const int jg = (g << 3) + (pp << 1) + blk;
                const int c = (w << 3) + (G << 2) + ch2;
                if (j == 0 && jg < NJ) Sg[((size_t)b * C_ + c) * NJ + jg] = v;
            }
        }
    }
}

// ---------------------------------------------------------------------------
// Kernel B: SNN, fully parallel phases. ROUND-15: block 256 -> 1024 threads.
// LDS (137 KB) pins occupancy at 1 block/CU, so 256 threads = 4 waves/CU =
// 1 wave/SIMD: zero latency hiding. 1024 threads = 16 waves/CU at the same
// LDS and identical math (all phases are tid-strided, race-free under any
// thread count).
// ---------------------------------------------------------------------------
__global__ __launch_bounds__(TB_, 1) void snnB(const float* __restrict__ Sg,
                                               const float* __restrict__ Wb,
                                               const float* __restrict__ Wic,
                                               const float* __restrict__ Wac,
                                               float* __restrict__ out) {
    __shared__ float sWb[HID_ * 321];      // 64,200 B (321%32==1: banks spread)
    __shared__ float sWic[HID_ * 51];      // 10,200 B
    __shared__ float sWac[OUT_ * 51];      //  2,040 B
    __shared__ u32   mask[T_ * 10];        //  4,960 B  (AN spike bits per step)
    __shared__ float cur[T_ * HID_];       // 24,800 B  (Bushy currents -> spkb)
    __shared__ float icur[T_ * HID_];      // 24,800 B  (IC currents -> spkic)
    __shared__ float acur[T_ * 12];        //  5,952 B  (AC currents, pad 12)

    const int b = blockIdx.x, tid = threadIdx.x;

    for (int i = tid; i < HID_ * 320; i += TB_) {
        int r = i / 320;
        sWb[r * 321 + (i - r * 320)] = Wb[i];
    }
    for (int i = tid; i < HID_ * HID_; i += TB_) {
        int r = i / 50;
        sWic[r * 51 + (i - r * 50)] = Wic[i];
    }
    for (int i = tid; i < OUT_ * HID_; i += TB_) {
        int r = i / 50;
        sWac[r * 51 + (i - r * 50)] = Wac[i];
    }

    // ---- AN spike bitmasks: word (t, wd) covers i in [32wd, 32wd+32)
    const float* Sb = Sg + (size_t)b * C_ * NJ;
    for (int idx = tid; idx < T_ * 10; idx += TB_) {
        int t = idx / 10, wd = idx - t * 10;
        u32 m = 0;
        int c_prev = -1;
        float env = 0.0f;
        for (int k = 0; k < 32; ++k) {
            int i = wd * 32 + k;
            int c = i / 10, s = i - c * 10;
            if (c != c_prev) {
                env = fmul(fadd(Sb[c * NJ + t], Sb[c * NJ + t + 1]), 0.00390625f);
                c_prev = c;
            }
            float sf = (s == 9) ? 1.5f : (float)(0.5 + (double)s * (1.0 / 9.0));
            if (fsub(fmul(env, sf), 0.5f) > 0.0f) m |= (1u << k);
        }
        mask[idx] = m;
    }
    __syncthreads();

    // ---- Bushy currents: 4 t-chains per weight-row pass (124 = 4*31)
    for (int k = tid; k < 31 * HID_; k += TB_) {
        int t0 = k / 50, h = k - t0 * 50;
        const float* wr = sWb + h * 321;
        const u32* m0 = mask + (t0     ) * 10;
        const u32* m1 = mask + (t0 + 31) * 10;
        const u32* m2 = mask + (t0 + 62) * 10;
        const u32* m3 = mask + (t0 + 93) * 10;
        float a0 = 0.0f, a1 = 0.0f, a2 = 0.0f, a3 = 0.0f;
#pragma unroll 8
        for (int i = 0; i < 320; ++i) {
            float wv = wr[i];
            const int wi = i >> 5, sh = i & 31;
            a0 = fadd(a0, ((m0[wi] >> sh) & 1u) ? wv : 0.0f);
            a1 = fadd(a1, ((m1[wi] >> sh) & 1u) ? wv : 0.0f);
            a2 = fadd(a2, ((m2[wi] >> sh) & 1u) ? wv : 0.0f);
            a3 = fadd(a3, ((m3[wi] >> sh) & 1u) ? wv : 0.0f);
        }
        cur[(t0     ) * 50 + h] = a0;
        cur[(t0 + 31) * 50 + h] = a1;
        cur[(t0 + 62) * 50 + h] = a2;
        cur[(t0 + 93) * 50 + h] = a3;
    }
    __syncthreads();

    // ---- Bushy membrane chains: one thread per neuron, spikes in-place
    if (tid < HID_) {
        float mem = 0.0f;
        for (int t = 0; t < T_; ++t) {
            float m = fadd(fmul(0.95f, mem), cur[t * 50 + tid]);
            float sp = (fsub(m, 1.0f) > 0.0f) ? 1.0f : 0.0f;
            mem = fsub(m, sp);
            cur[t * 50 + tid] = sp;          // own slot only: race-free
        }
    }
    __syncthreads();

    // ---- IC currents: 6200 independent sequential-g chains
    for (int idx = tid; idx < T_ * HID_; idx += TB_) {
        int t = idx / 50, h = idx - t * 50;
        const float* wr = sWic + h * 51;
        const float* sb = cur + t * 50;
        float acc = 0.0f;
#pragma unroll
        for (int g = 0; g < HID_; ++g) acc = fadd(acc, fmul(sb[g], wr[g]));
        icur[idx] = acc;
    }
    __syncthreads();

    // ---- IC membrane chains
    if (tid < HID_) {
        float mem = 0.0f;
        for (int t = 0; t < T_; ++t) {
            float m = fadd(fmul(0.95f, mem), icur[t * 50 + tid]);
            float sp = (fsub(m, 1.0f) > 0.0f) ? 1.0f : 0.0f;
            mem = fsub(m, sp);
            icur[t * 50 + tid] = sp;
        }
    }
    __syncthreads();

    // ---- AC currents: 1240 chains
    for (int idx = tid; idx < T_ * OUT_; idx += TB_) {
        int t = idx / 10, o = idx - t * 10;
        const float* wr = sWac + o * 51;
        const float* sb = icur + t * 50;
        float acc = 0.0f;
#pragma unroll
        for (int g = 0; g < HID_; ++g) acc = fadd(acc, fmul(sb[g], wr[g]));
        acur[t * 12 + o] = acc;
    }
    __syncthreads();

    // ---- AC membrane chains + output stores
    if (tid < OUT_) {
        float mem = 0.0f;
        for (int t = 0; t < T_; ++t) {
            float m = fadd(fmul(0.95f, mem), acur[t * 12 + tid]);
            float sp = (fsub(m, 1.0f) > 0.0f) ? 1.0f : 0.0f;
            float mo = fsub(m, sp);
            mem = mo;
            size_t base = ((size_t)b * T_ + t) * OUT_ + tid;
            out[base] = sp;
            out[(size_t)(B_ * T_ * OUT_) + base] = mo;
        }
    }
}

// ---------------------------------------------------------------------------
extern "C" void kernel_launch(void* const* d_in, const int* in_sizes, int n_in,
                              void* d_out, int out_size, void* d_ws, size_t ws_size,
                              hipStream_t stream) {
    (void)in_sizes; (void)n_in; (void)out_size; (void)ws_size;
    const float* audio = (const float*)d_in[0];
    const float* gt    = (const float*)d_in[1];
    const float* Wb    = (const float*)d_in[2];
    const float* Wic   = (const float*)d_in[3];
    const float* Wac   = (const float*)d_in[4];

    float* Sg = (float*)d_ws;   // needs 256*32*125*4 = 4,096,000 B of ws

    convA<<<dim3(B_, 16), dim3(256), 0, stream>>>(audio, gt, Sg);
    snnB<<<dim3(B_), dim3(TB_), 0, stream>>>(Sg, Wb, Wic, Wac, (float*)d_out);
}

// Round 2
// 333.578 us; speedup vs baseline: 1.5342x; 1.1074x over previous
//
#include <hip/hip_runtime.h>

// Problem dims
#define B_   256
#define N_   16000
#define C_   32
#define K_   64
#define T_   124
#define NJ   125      // 128-sample half-window block sums, j = 0..124
#define HID_ 50
#define OUT_ 10
#define TB_  1024     // snnB block size

typedef unsigned int u32;
typedef float v2f __attribute__((ext_vector_type(2)));
struct __align__(16) f2x2 { v2f lo, hi; };

// Exact single f32 ops (prevent fma contraction / reassociation).
__device__ __forceinline__ float fadd(float a, float b) { return __fadd_rn(a, b); }
__device__ __forceinline__ float fmul(float a, float b) { return __fmul_rn(a, b); }
__device__ __forceinline__ float fsub(float a, float b) { return __fsub_rn(a, b); }

// Packed f32 FMA: y.lo += a.lo*tap, y.hi += a.hi*tap, tap = slot k of pair-pair T,
// broadcast via VOP3P op_sel (no splat movs). Each half is an IEEE f32 FMA ==
// fmaf: bit-identical to the scalar version. k is compile-time after unroll ->
// dead branches fold.
__device__ __forceinline__ void PKFMA(v2f& y, v2f a, const f2x2& T, int k) {
    switch (k) {
    case 0:  asm("v_pk_fma_f32 %0, %1, %2, %0 op_sel:[0,0,0] op_sel_hi:[1,0,1]"
                 : "+v"(y) : "v"(a), "v"(T.lo)); break;
    case 1:  asm("v_pk_fma_f32 %0, %1, %2, %0 op_sel:[0,1,0] op_sel_hi:[1,1,1]"
                 : "+v"(y) : "v"(a), "v"(T.lo)); break;
    case 2:  asm("v_pk_fma_f32 %0, %1, %2, %0 op_sel:[0,0,0] op_sel_hi:[1,0,1]"
                 : "+v"(y) : "v"(a), "v"(T.hi)); break;
    default: asm("v_pk_fma_f32 %0, %1, %2, %0 op_sel:[0,1,0] op_sel_hi:[1,1,1]"
                 : "+v"(y) : "v"(a), "v"(T.hi)); break;
    }
}

// ---------------------------------------------------------------------------
// Kernel A: conv (SAME pad_lo=31, correlation, sequential-k f32 FMA) + relu +
// numpy-pairwise 128-block sums -> Sg[b][c][j].
//
// ROUND-16: v_pk_fma_f32. Scalar v_fma issue rate caps the chip at ~103-157
// TF; packed f32 doubles FLOP/instruction. pp sub-tiles packed in pairs
// (P = pp>>1): audio staged INTERLEAVED in LDS (ab[2i]=s0[i], ab[2i+1]=s1[i])
// so one b128 read yields two (a_pp0,a_pp1) packed pairs x 2 e-steps. Taps
// broadcast via op_sel. Per-output accumulation order (q asc, e asc)
// unchanged: bit-exact vs round-15.
// Interleave makes audio lane stride 32B (4-way bank conflict) -> XOR-swizzle
// j ^= ((j>>5)&1)<<2 (bijective, applied on write and read): conflict-free.
// Regs ~115: launch_bounds(256,4) caps VGPR<=128 -> 4 waves/SIMD.
// ---------------------------------------------------------------------------
__global__ __launch_bounds__(256, 4) void convA(const float* __restrict__ audio,
                                                const float* __restrict__ gt,
                                                float* __restrict__ Sg) {
    __shared__ __align__(16) float abI[1280];         //  5,120 B  [P][640] interleaved
    __shared__ __align__(16) float kLDS[C_ * K_];     //  8,192 B
    __shared__ __align__(16) float ybuf[4][4][264];   // 16,896 B [wave][ch][2blk*132]

    const int b = blockIdx.x, g = blockIdx.y;
    const int tid = threadIdx.x, w = tid >> 6, lane = tid & 63;
    const float* arow = audio + (size_t)b * N_;

    const int origin = (g << 10) - 32;
    // Interleaved staging: logical j = 2*i + h  <->  sample origin + P*512 + h*256 + i
    for (int idx = tid; idx < 1280; idx += 256) {
        int P = idx / 640, j = idx - P * 640;
        int ii = j >> 1, h = j & 1;
        int gi = origin + (P << 9) + (h << 8) + ii;
        float v = (gi >= 0 && gi < N_) ? arow[gi] : 0.0f;
        abI[P * 640 + (j ^ (((j >> 5) & 1) << 2))] = v;
    }
    for (int i = tid; i < C_ * K_; i += 256) kLDS[i] = gt[i];
    __syncthreads();

    for (int G = 0; G < 2; ++G) {
        const float* kgrp = &kLDS[((w << 3) + (G << 2)) << 6];  // ch base row

        v2f Y[2][4][4];   // [P][ch][d]; lo = pp=2P, hi = pp=2P+1
#pragma unroll
        for (int P = 0; P < 2; ++P)
#pragma unroll
            for (int ch = 0; ch < 4; ++ch)
#pragma unroll
                for (int d = 0; d < 4; ++d) { Y[P][ch][d].x = 0.0f; Y[P][ch][d].y = 0.0f; }

        f2x2 Tp[4];

        // ---- q = 0 peel: k = e-1-d, only k>=0 terms (all from Tc)
        {
            f2x2 Tc[4];
#pragma unroll
            for (int ch = 0; ch < 4; ++ch)
                Tc[ch] = *(const f2x2*)(kgrp + (ch << 6));
            const int u = lane;
            const int p1 = (u << 3) ^ (((u >> 2) & 1) << 2);
#pragma unroll
            for (int P = 0; P < 2; ++P) {
                const float* abP = abI + P * 640;
                const f2x2 A0 = *(const f2x2*)(abP + p1);
                const f2x2 A1 = *(const f2x2*)(abP + (p1 ^ 4));
#pragma unroll
                for (int e = 0; e < 4; ++e) {
                    const v2f a = (e == 0) ? A0.lo : (e == 1) ? A0.hi
                                : (e == 2) ? A1.lo : A1.hi;
#pragma unroll
                    for (int ch = 0; ch < 4; ++ch)
#pragma unroll
                        for (int d = 0; d < 4; ++d) {
                            const int kb = e - 1 - d;          // compile-time
                            if (kb >= 0) PKFMA(Y[P][ch][d], a, Tc[ch], kb);
                        }
                }
            }
#pragma unroll
            for (int ch = 0; ch < 4; ++ch) Tp[ch] = Tc[ch];
        }

        // ---- q = 1..15: boundary-free, NOT unrolled (live set = 1 iter)
#pragma unroll 1
        for (int q = 1; q < 16; ++q) {
            f2x2 Tc[4];
#pragma unroll
            for (int ch = 0; ch < 4; ++ch)
                Tc[ch] = *(const f2x2*)(kgrp + (ch << 6) + (q << 2));
            const int u = lane + q;
            const int p1 = (u << 3) ^ (((u >> 2) & 1) << 2);
#pragma unroll
            for (int P = 0; P < 2; ++P) {
                const float* abP = abI + P * 640;
                const f2x2 A0 = *(const f2x2*)(abP + p1);
                const f2x2 A1 = *(const f2x2*)(abP + (p1 ^ 4));
#pragma unroll
                for (int e = 0; e < 4; ++e) {
                    const v2f a = (e == 0) ? A0.lo : (e == 1) ? A0.hi
                                : (e == 2) ? A1.lo : A1.hi;
#pragma unroll
                    for (int ch = 0; ch < 4; ++ch)
#pragma unroll
                        for (int d = 0; d < 4; ++d) {
                            const int ts = e - 1 - d;          // compile-time
                            if (ts >= 0) PKFMA(Y[P][ch][d], a, Tc[ch], ts);
                            else         PKFMA(Y[P][ch][d], a, Tp[ch], 4 + ts);
                        }
                }
            }
#pragma unroll
            for (int ch = 0; ch < 4; ++ch) Tp[ch] = Tc[ch];
        }

        // ---- q = 16 peel: only ts<0 (Tp) terms
        {
            const int u = lane + 16;
            const int p1 = (u << 3) ^ (((u >> 2) & 1) << 2);
#pragma unroll
            for (int P = 0; P < 2; ++P) {
                const float* abP = abI + P * 640;
                const f2x2 A0 = *(const f2x2*)(abP + p1);
                const f2x2 A1 = *(const f2x2*)(abP + (p1 ^ 4));
#pragma unroll
                for (int e = 0; e < 4; ++e) {
                    const v2f a = (e == 0) ? A0.lo : (e == 1) ? A0.hi
                                : (e == 2) ? A1.lo : A1.hi;
#pragma unroll
                    for (int ch = 0; ch < 4; ++ch)
#pragma unroll
                        for (int d = 0; d < 4; ++d) {
                            const int ts = e - 1 - d;          // compile-time
                            if (ts < 0) PKFMA(Y[P][ch][d], a, Tp[ch], 4 + ts);
                        }
                }
            }
        }

        // ---- epilogue per pp (identical math/order to round-15)
#pragma unroll
        for (int pp = 0; pp < 4; ++pp) {
            const int P = pp >> 1, h = pp & 1;
#pragma unroll
            for (int ch = 0; ch < 4; ++ch) {
                float4 z;
                z.x = fmaxf(h ? Y[P][ch][0].y : Y[P][ch][0].x, 0.0f);
                z.y = fmaxf(h ? Y[P][ch][1].y : Y[P][ch][1].x, 0.0f);
                z.z = fmaxf(h ? Y[P][ch][2].y : Y[P][ch][2].x, 0.0f);
                z.w = fmaxf(h ? Y[P][ch][3].y : Y[P][ch][3].x, 0.0f);
                *(float4*)(&ybuf[w][ch][((lane >> 5) * 132) + ((lane & 31) << 2)]) = z;
            }
            // numpy pairwise-128: 64 lanes = 4ch x 2blk x 8slots.
            {
                const int ch2 = lane >> 4, blk = (lane >> 3) & 1, j = lane & 7;
                const float* yb = &ybuf[w][ch2][blk * 132 + j];
                float r = yb[0];
#pragma unroll
                for (int m = 1; m < 16; ++m) r = fadd(r, yb[m << 3]);
                float v = fadd(r, __shfl_xor(r, 1));
                v = fadd(v, __shfl_xor(v, 2));
                v = fadd(v, __shfl_xor(v, 4));
                const int jg = (g << 3) + (pp << 1) + blk;
                const int c = (w << 3) + (G << 2) + ch2;
                if (j == 0 && jg < NJ) Sg[((size_t)b * C_ + c) * NJ + jg] = v;
            }
        }
    }
}

// ---------------------------------------------------------------------------
// Kernel B: SNN, fully parallel phases (unchanged from round-15; 1024 thr).
// ---------------------------------------------------------------------------
__global__ __launch_bounds__(TB_, 1) void snnB(const float* __restrict__ Sg,
                                               const float* __restrict__ Wb,
                                               const float* __restrict__ Wic,
                                               const float* __restrict__ Wac,
                                               float* __restrict__ out) {
    __shared__ float sWb[HID_ * 321];      // 64,200 B (321%32==1: banks spread)
    __shared__ float sWic[HID_ * 51];      // 10,200 B
    __shared__ float sWac[OUT_ * 51];      //  2,040 B
    __shared__ u32   mask[T_ * 10];        //  4,960 B  (AN spike bits per step)
    __shared__ float cur[T_ * HID_];       // 24,800 B  (Bushy currents -> spkb)
    __shared__ float icur[T_ * HID_];      // 24,800 B  (IC currents -> spkic)
    __shared__ float acur[T_ * 12];        //  5,952 B  (AC currents, pad 12)

    const int b = blockIdx.x, tid = threadIdx.x;

    for (int i = tid; i < HID_ * 320; i += TB_) {
        int r = i / 320;
        sWb[r * 321 + (i - r * 320)] = Wb[i];
    }
    for (int i = tid; i < HID_ * HID_; i += TB_) {
        int r = i / 50;
        sWic[r * 51 + (i - r * 50)] = Wic[i];
    }
    for (int i = tid; i < OUT_ * HID_; i += TB_) {
        int r = i / 50;
        sWac[r * 51 + (i - r * 50)] = Wac[i];
    }

    // ---- AN spike bitmasks: word (t, wd) covers i in [32wd, 32wd+32)
    const float* Sb = Sg + (size_t)b * C_ * NJ;
    for (int idx = tid; idx < T_ * 10; idx += TB_) {
        int t = idx / 10, wd = idx - t * 10;
        u32 m = 0;
        int c_prev = -1;
        float env = 0.0f;
        for (int k = 0; k < 32; ++k) {
            int i = wd * 32 + k;
            int c = i / 10, s = i - c * 10;
            if (c != c_prev) {
                env = fmul(fadd(Sb[c * NJ + t], Sb[c * NJ + t + 1]), 0.00390625f);
                c_prev = c;
            }
            float sf = (s == 9) ? 1.5f : (float)(0.5 + (double)s * (1.0 / 9.0));
            if (fsub(fmul(env, sf), 0.5f) > 0.0f) m |= (1u << k);
        }
        mask[idx] = m;
    }
    __syncthreads();

    // ---- Bushy currents: 4 t-chains per weight-row pass (124 = 4*31)
    for (int k = tid; k < 31 * HID_; k += TB_) {
        int t0 = k / 50, h = k - t0 * 50;
        const float* wr = sWb + h * 321;
        const u32* m0 = mask + (t0     ) * 10;
        const u32* m1 = mask + (t0 + 31) * 10;
        const u32* m2 = mask + (t0 + 62) * 10;
        const u32* m3 = mask + (t0 + 93) * 10;
        float a0 = 0.0f, a1 = 0.0f, a2 = 0.0f, a3 = 0.0f;
#pragma unroll 8
        for (int i = 0; i < 320; ++i) {
            float wv = wr[i];
            const int wi = i >> 5, sh = i & 31;
            a0 = fadd(a0, ((m0[wi] >> sh) & 1u) ? wv : 0.0f);
            a1 = fadd(a1, ((m1[wi] >> sh) & 1u) ? wv : 0.0f);
            a2 = fadd(a2, ((m2[wi] >> sh) & 1u) ? wv : 0.0f);
            a3 = fadd(a3, ((m3[wi] >> sh) & 1u) ? wv : 0.0f);
        }
        cur[(t0     ) * 50 + h] = a0;
        cur[(t0 + 31) * 50 + h] = a1;
        cur[(t0 + 62) * 50 + h] = a2;
        cur[(t0 + 93) * 50 + h] = a3;
    }
    __syncthreads();

    // ---- Bushy membrane chains: one thread per neuron, spikes in-place
    if (tid < HID_) {
        float mem = 0.0f;
        for (int t = 0; t < T_; ++t) {
            float m = fadd(fmul(0.95f, mem), cur[t * 50 + tid]);
            float sp = (fsub(m, 1.0f) > 0.0f) ? 1.0f : 0.0f;
            mem = fsub(m, sp);
            cur[t * 50 + tid] = sp;          // own slot only: race-free
        }
    }
    __syncthreads();

    // ---- IC currents: 6200 independent sequential-g chains
    for (int idx = tid; idx < T_ * HID_; idx += TB_) {
        int t = idx / 50, h = idx - t * 50;
        const float* wr = sWic + h * 51;
        const float* sb = cur + t * 50;
        float acc = 0.0f;
#pragma unroll
        for (int g = 0; g < HID_; ++g) acc = fadd(acc, fmul(sb[g], wr[g]));
        icur[idx] = acc;
    }
    __syncthreads();

    // ---- IC membrane chains
    if (tid < HID_) {
        float mem = 0.0f;
        for (int t = 0; t < T_; ++t) {
            float m = fadd(fmul(0.95f, mem), icur[t * 50 + tid]);
            float sp = (fsub(m, 1.0f) > 0.0f) ? 1.0f : 0.0f;
            mem = fsub(m, sp);
            icur[t * 50 + tid] = sp;
        }
    }
    __syncthreads();

    // ---- AC currents: 1240 chains
    for (int idx = tid; idx < T_ * OUT_; idx += TB_) {
        int t = idx / 10, o = idx - t * 10;
        const float* wr = sWac + o * 51;
        const float* sb = icur + t * 50;
        float acc = 0.0f;
#pragma unroll
        for (int g = 0; g < HID_; ++g) acc = fadd(acc, fmul(sb[g], wr[g]));
        acur[t * 12 + o] = acc;
    }
    __syncthreads();

    // ---- AC membrane chains + output stores
    if (tid < OUT_) {
        float mem = 0.0f;
        for (int t = 0; t < T_; ++t) {
            float m = fadd(fmul(0.95f, mem), acur[t * 12 + tid]);
            float sp = (fsub(m, 1.0f) > 0.0f) ? 1.0f : 0.0f;
            float mo = fsub(m, sp);
            mem = mo;
            size_t base = ((size_t)b * T_ + t) * OUT_ + tid;
            out[base] = sp;
            out[(size_t)(B_ * T_ * OUT_) + base] = mo;
        }
    }
}

// ---------------------------------------------------------------------------
extern "C" void kernel_launch(void* const* d_in, const int* in_sizes, int n_in,
                              void* d_out, int out_size, void* d_ws, size_t ws_size,
                              hipStream_t stream) {
    (void)in_sizes; (void)n_in; (void)out_size; (void)ws_size;
    const float* audio = (const float*)d_in[0];
    const float* gt    = (const float*)d_in[1];
    const float* Wb    = (const float*)d_in[2];
    const float* Wic   = (const float*)d_in[3];
    const float* Wac   = (const float*)d_in[4];

    float* Sg = (float*)d_ws;   // needs 256*32*125*4 = 4,096,000 B of ws

    convA<<<dim3(B_, 16), dim3(256), 0, stream>>>(audio, gt, Sg);
    snnB<<<dim3(B_), dim3(TB_), 0, stream>>>(Sg, Wb, Wic, Wac, (float*)d_out);
}

// Round 3
// 325.942 us; speedup vs baseline: 1.5701x; 1.0234x over previous
//
#include <hip/hip_runtime.h>

// Problem dims
#define B_   256
#define N_   16000
#define C_   32
#define K_   64
#define T_   124
#define NJ   125      // 128-sample half-window block sums, j = 0..124
#define HID_ 50
#define OUT_ 10
#define TB_  1024     // snnB block size
#define CURS 52       // padded stride for cur/icur (float4-aligned)

typedef unsigned int u32;
typedef float v2f __attribute__((ext_vector_type(2)));
struct __align__(16) f2x2 { v2f lo, hi; };

// Exact single f32 ops (prevent fma contraction / reassociation).
__device__ __forceinline__ float fadd(float a, float b) { return __fadd_rn(a, b); }
__device__ __forceinline__ float fmul(float a, float b) { return __fmul_rn(a, b); }
__device__ __forceinline__ float fsub(float a, float b) { return __fsub_rn(a, b); }

// Packed f32 FMA: y.lo += a.lo*tap, y.hi += a.hi*tap, tap = slot k of pair-pair T,
// broadcast via VOP3P op_sel. T lives in SGPRs (s_load'd, wave-uniform): VOP3P
// permits one SGPR source. Each half is an IEEE f32 FMA == fmaf: bit-identical.
__device__ __forceinline__ void PKFMA(v2f& y, v2f a, const f2x2& T, int k) {
    switch (k) {
    case 0:  asm("v_pk_fma_f32 %0, %1, %2, %0 op_sel:[0,0,0] op_sel_hi:[1,0,1]"
                 : "+v"(y) : "v"(a), "s"(T.lo)); break;
    case 1:  asm("v_pk_fma_f32 %0, %1, %2, %0 op_sel:[0,1,0] op_sel_hi:[1,1,1]"
                 : "+v"(y) : "v"(a), "s"(T.lo)); break;
    case 2:  asm("v_pk_fma_f32 %0, %1, %2, %0 op_sel:[0,0,0] op_sel_hi:[1,0,1]"
                 : "+v"(y) : "v"(a), "s"(T.hi)); break;
    default: asm("v_pk_fma_f32 %0, %1, %2, %0 op_sel:[0,1,0] op_sel_hi:[1,1,1]"
                 : "+v"(y) : "v"(a), "s"(T.hi)); break;
    }
}

// ---------------------------------------------------------------------------
// Kernel A: conv (SAME pad_lo=31, correlation, sequential-k f32 FMA) + relu +
// numpy-pairwise 128-block sums -> Sg[b][c][j].
//
// ROUND-17: taps via SMEM. Tap addresses are wave-uniform: route them through
// a readfirstlane-uniformed global pointer -> s_load_dwordx4 (scalar cache
// broadcast). Kills kLDS (8 KB), 4 ds_read_b128/q, and all Tp v_movs (the
// (q-1,q) window is re-loaded scalar each iter). LDS 30.2 -> 21.5 KB ->
// up to 7 blocks/CU (was ~3.3): r16 was latency-bound (real VALU work ~74 us
// of 198; occupancy 41%). Per-output accumulation order (q asc, e asc)
// unchanged: bit-exact vs rounds 15/16.
// ---------------------------------------------------------------------------
__global__ __launch_bounds__(256, 6) void convA(const float* __restrict__ audio,
                                                const float* __restrict__ gt,
                                                float* __restrict__ Sg) {
    __shared__ __align__(16) float abI[1280];         //  5,120 B  [P][640] interleaved
    __shared__ __align__(16) float ybuf[4][4][264];   // 16,896 B [wave][ch][2blk*132]

    const int b = blockIdx.x, g = blockIdx.y;
    const int tid = threadIdx.x, w = tid >> 6, lane = tid & 63;
    const float* arow = audio + (size_t)b * N_;

    const int origin = (g << 10) - 32;
    // Interleaved staging: logical j = 2*i + h  <->  sample origin + P*512 + h*256 + i
    for (int idx = tid; idx < 1280; idx += 256) {
        int P = idx / 640, j = idx - P * 640;
        int ii = j >> 1, h = j & 1;
        int gi = origin + (P << 9) + (h << 8) + ii;
        float v = (gi >= 0 && gi < N_) ? arow[gi] : 0.0f;
        abI[P * 640 + (j ^ (((j >> 5) & 1) << 2))] = v;
    }
    __syncthreads();

    for (int G = 0; G < 2; ++G) {
        // wave-uniform tap row base -> scalar loads
        const int rowbase = __builtin_amdgcn_readfirstlane(((w << 3) + (G << 2)) << 6);
        const float* kg = gt + rowbase;

        v2f Y[2][4][4];   // [P][ch][d]; lo = pp=2P, hi = pp=2P+1
#pragma unroll
        for (int P = 0; P < 2; ++P)
#pragma unroll
            for (int ch = 0; ch < 4; ++ch)
#pragma unroll
                for (int d = 0; d < 4; ++d) { Y[P][ch][d].x = 0.0f; Y[P][ch][d].y = 0.0f; }

        // ---- q = 0 peel: k = e-1-d, only k>=0 terms (all from Tc)
        {
            f2x2 Tc[4];
#pragma unroll
            for (int ch = 0; ch < 4; ++ch)
                Tc[ch] = *(const f2x2*)(kg + (ch << 6));
            const int u = lane;
            const int p1 = (u << 3) ^ (((u >> 2) & 1) << 2);
#pragma unroll
            for (int P = 0; P < 2; ++P) {
                const float* abP = abI + P * 640;
                const f2x2 A0 = *(const f2x2*)(abP + p1);
                const f2x2 A1 = *(const f2x2*)(abP + (p1 ^ 4));
#pragma unroll
                for (int e = 0; e < 4; ++e) {
                    const v2f a = (e == 0) ? A0.lo : (e == 1) ? A0.hi
                                : (e == 2) ? A1.lo : A1.hi;
#pragma unroll
                    for (int ch = 0; ch < 4; ++ch)
#pragma unroll
                        for (int d = 0; d < 4; ++d) {
                            const int kb = e - 1 - d;          // compile-time
                            if (kb >= 0) PKFMA(Y[P][ch][d], a, Tc[ch], kb);
                        }
                }
            }
        }

        // ---- q = 1..15: boundary-free, NOT unrolled (live set = 1 iter)
#pragma unroll 1
        for (int q = 1; q < 16; ++q) {
            f2x2 Tm[4], Tc[4];   // taps 4(q-1)+{0..3} and 4q+{0..3} (SGPR)
#pragma unroll
            for (int ch = 0; ch < 4; ++ch) {
                Tm[ch] = *(const f2x2*)(kg + (ch << 6) + ((q - 1) << 2));
                Tc[ch] = *(const f2x2*)(kg + (ch << 6) + (q << 2));
            }
            const int u = lane + q;
            const int p1 = (u << 3) ^ (((u >> 2) & 1) << 2);
#pragma unroll
            for (int P = 0; P < 2; ++P) {
                const float* abP = abI + P * 640;
                const f2x2 A0 = *(const f2x2*)(abP + p1);
                const f2x2 A1 = *(const f2x2*)(abP + (p1 ^ 4));
#pragma unroll
                for (int e = 0; e < 4; ++e) {
                    const v2f a = (e == 0) ? A0.lo : (e == 1) ? A0.hi
                                : (e == 2) ? A1.lo : A1.hi;
#pragma unroll
                    for (int ch = 0; ch < 4; ++ch)
#pragma unroll
                        for (int d = 0; d < 4; ++d) {
                            const int ts = e - 1 - d;          // compile-time
                            if (ts >= 0) PKFMA(Y[P][ch][d], a, Tc[ch], ts);
                            else         PKFMA(Y[P][ch][d], a, Tm[ch], 4 + ts);
                        }
                }
            }
        }

        // ---- q = 16 peel: only ts<0 terms (taps 60..63)
        {
            f2x2 Tm[4];
#pragma unroll
            for (int ch = 0; ch < 4; ++ch)
                Tm[ch] = *(const f2x2*)(kg + (ch << 6) + 60);
            const int u = lane + 16;
            const int p1 = (u << 3) ^ (((u >> 2) & 1) << 2);
#pragma unroll
            for (int P = 0; P < 2; ++P) {
                const float* abP = abI + P * 640;
                const f2x2 A0 = *(const f2x2*)(abP + p1);
                const f2x2 A1 = *(const f2x2*)(abP + (p1 ^ 4));
#pragma unroll
                for (int e = 0; e < 4; ++e) {
                    const v2f a = (e == 0) ? A0.lo : (e == 1) ? A0.hi
                                : (e == 2) ? A1.lo : A1.hi;
#pragma unroll
                    for (int ch = 0; ch < 4; ++ch)
#pragma unroll
                        for (int d = 0; d < 4; ++d) {
                            const int ts = e - 1 - d;          // compile-time
                            if (ts < 0) PKFMA(Y[P][ch][d], a, Tm[ch], 4 + ts);
                        }
                }
            }
        }

        // ---- epilogue per pp (identical math/order to rounds 15/16)
#pragma unroll
        for (int pp = 0; pp < 4; ++pp) {
            const int P = pp >> 1, h = pp & 1;
#pragma unroll
            for (int ch = 0; ch < 4; ++ch) {
                float4 z;
                z.x = fmaxf(h ? Y[P][ch][0].y : Y[P][ch][0].x, 0.0f);
                z.y = fmaxf(h ? Y[P][ch][1].y : Y[P][ch][1].x, 0.0f);
                z.z = fmaxf(h ? Y[P][ch][2].y : Y[P][ch][2].x, 0.0f);
                z.w = fmaxf(h ? Y[P][ch][3].y : Y[P][ch][3].x, 0.0f);
                *(float4*)(&ybuf[w][ch][((lane >> 5) * 132) + ((lane & 31) << 2)]) = z;
            }
            // numpy pairwise-128: 64 lanes = 4ch x 2blk x 8slots.
            {
                const int ch2 = lane >> 4, blk = (lane >> 3) & 1, j = lane & 7;
                const float* yb = &ybuf[w][ch2][blk * 132 + j];
                float r = yb[0];
#pragma unroll
                for (int m = 1; m < 16; ++m) r = fadd(r, yb[m << 3]);
                float v = fadd(r, __shfl_xor(r, 1));
                v = fadd(v, __shfl_xor(v, 2));
                v = fadd(v, __shfl_xor(v, 4));
                const int jg = (g << 3) + (pp << 1) + blk;
                const int c = (w << 3) + (G << 2) + ch2;
                if (j == 0 && jg < NJ) Sg[((size_t)b * C_ + c) * NJ + jg] = v;
            }
        }
    }
}

// ---------------------------------------------------------------------------
// Kernel B: SNN. ROUND-17:
//  - bushy: 8 t-chains/thread (800 items = 1 balanced round), bit-select via
//    v_bfe_i32 sign-mask + and + fadd (3 inst/chain). Adding +0.0 on clear
//    bits is identical to the old cndmask path (acc never -0.0).
//  - IC/AC: fmaf (products of 0/1 spikes are exact -> bit-identical to
//    fadd(fmul)) + float4 LDS reads via stride-52 cur/icur padding.
// Accumulation orders everywhere unchanged: bit-exact.
// ---------------------------------------------------------------------------
__global__ __launch_bounds__(TB_, 1) void snnB(const float* __restrict__ Sg,
                                               const float* __restrict__ Wb,
                                               const float* __restrict__ Wic,
                                               const float* __restrict__ Wac,
                                               float* __restrict__ out) {
    __shared__ float sWb[HID_ * 321];                 // 64,200 B (321%32==1)
    __shared__ __align__(16) float sWic[HID_ * 52];   // 10,400 B
    __shared__ __align__(16) float sWac[OUT_ * 52];   //  2,080 B
    __shared__ u32   mask[128 * 10];                  //  5,120 B (rows 124..127 zero)
    __shared__ __align__(16) float cur[T_ * CURS];    // 25,792 B
    __shared__ __align__(16) float icur[T_ * CURS];   // 25,792 B
    __shared__ float acur[T_ * 12];                   //  5,952 B   (total ~139.3 KB)

    const int b = blockIdx.x, tid = threadIdx.x;

    for (int i = tid; i < HID_ * 320; i += TB_) {
        int r = i / 320;
        sWb[r * 321 + (i - r * 320)] = Wb[i];
    }
    for (int i = tid; i < HID_ * HID_; i += TB_) {
        int r = i / 50;
        sWic[r * 52 + (i - r * 50)] = Wic[i];
    }
    for (int i = tid; i < OUT_ * HID_; i += TB_) {
        int r = i / 50;
        sWac[r * 52 + (i - r * 50)] = Wac[i];
    }

    // ---- AN spike bitmasks: word (t, wd) covers i in [32wd, 32wd+32)
    const float* Sb = Sg + (size_t)b * C_ * NJ;
    for (int idx = tid; idx < 1280; idx += TB_) {
        if (idx >= T_ * 10) { mask[idx] = 0; continue; }
        int t = idx / 10, wd = idx - t * 10;
        u32 m = 0;
        int c_prev = -1;
        float env = 0.0f;
        for (int k = 0; k < 32; ++k) {
            int i = wd * 32 + k;
            int c = i / 10, s = i - c * 10;
            if (c != c_prev) {
                env = fmul(fadd(Sb[c * NJ + t], Sb[c * NJ + t + 1]), 0.00390625f);
                c_prev = c;
            }
            float sf = (s == 9) ? 1.5f : (float)(0.5 + (double)s * (1.0 / 9.0));
            if (fsub(fmul(env, sf), 0.5f) > 0.0f) m |= (1u << k);
        }
        mask[idx] = m;
    }
    __syncthreads();

    // ---- Bushy currents: 8 t-chains per weight-row pass (t = t0 + 16m)
    if (tid < 16 * HID_) {
        const int t0 = tid / 50, h = tid - t0 * 50;
        const float* wr = sWb + h * 321;
        const u32* mrow = mask + t0 * 10;
        float a0 = 0.0f, a1 = 0.0f, a2 = 0.0f, a3 = 0.0f;
        float a4 = 0.0f, a5 = 0.0f, a6 = 0.0f, a7 = 0.0f;
#pragma unroll 1
        for (int wi = 0; wi < 10; ++wi) {
            const u32 w0 = mrow[wi], w1 = mrow[160 + wi];
            const u32 w2 = mrow[320 + wi], w3 = mrow[480 + wi];
            const u32 w4 = mrow[640 + wi], w5 = mrow[800 + wi];
            const u32 w6 = mrow[960 + wi], w7 = mrow[1120 + wi];
#pragma unroll
            for (int b2 = 0; b2 < 32; ++b2) {
                const float wv = wr[(wi << 5) + b2];
                const int iw = __float_as_int(wv);
                a0 = fadd(a0, __int_as_float(iw & __builtin_amdgcn_sbfe((int)w0, b2, 1)));
                a1 = fadd(a1, __int_as_float(iw & __builtin_amdgcn_sbfe((int)w1, b2, 1)));
                a2 = fadd(a2, __int_as_float(iw & __builtin_amdgcn_sbfe((int)w2, b2, 1)));
                a3 = fadd(a3, __int_as_float(iw & __builtin_amdgcn_sbfe((int)w3, b2, 1)));
                a4 = fadd(a4, __int_as_float(iw & __builtin_amdgcn_sbfe((int)w4, b2, 1)));
                a5 = fadd(a5, __int_as_float(iw & __builtin_amdgcn_sbfe((int)w5, b2, 1)));
                a6 = fadd(a6, __int_as_float(iw & __builtin_amdgcn_sbfe((int)w6, b2, 1)));
                a7 = fadd(a7, __int_as_float(iw & __builtin_amdgcn_sbfe((int)w7, b2, 1)));
            }
        }
        cur[(t0      ) * CURS + h] = a0;
        cur[(t0 + 16 ) * CURS + h] = a1;
        cur[(t0 + 32 ) * CURS + h] = a2;
        cur[(t0 + 48 ) * CURS + h] = a3;
        cur[(t0 + 64 ) * CURS + h] = a4;
        cur[(t0 + 80 ) * CURS + h] = a5;
        cur[(t0 + 96 ) * CURS + h] = a6;
        if (t0 + 112 < T_) cur[(t0 + 112) * CURS + h] = a7;
    }
    __syncthreads();

    // ---- Bushy membrane chains: one thread per neuron, spikes in-place
    if (tid < HID_) {
        float mem = 0.0f;
        for (int t = 0; t < T_; ++t) {
            float m = fadd(fmul(0.95f, mem), cur[t * CURS + tid]);
            float sp = (fsub(m, 1.0f) > 0.0f) ? 1.0f : 0.0f;
            mem = fsub(m, sp);
            cur[t * CURS + tid] = sp;        // own slot only: race-free
        }
    }
    __syncthreads();

    // ---- IC currents: 6200 chains, float4 reads + fmaf (bit-exact: spikes 0/1)
    for (int idx = tid; idx < T_ * HID_; idx += TB_) {
        int t = idx / 50, h = idx - t * 50;
        const float* wr = sWic + h * 52;
        const float* sb = cur + t * CURS;
        float acc = 0.0f;
#pragma unroll
        for (int g4 = 0; g4 < 12; ++g4) {
            const float4 s4 = *(const float4*)(sb + (g4 << 2));
            const float4 w4 = *(const float4*)(wr + (g4 << 2));
            acc = fmaf(s4.x, w4.x, acc);
            acc = fmaf(s4.y, w4.y, acc);
            acc = fmaf(s4.z, w4.z, acc);
            acc = fmaf(s4.w, w4.w, acc);
        }
        acc = fmaf(sb[48], wr[48], acc);
        acc = fmaf(sb[49], wr[49], acc);
        icur[t * CURS + h] = acc;
    }
    __syncthreads();

    // ---- IC membrane chains
    if (tid < HID_) {
        float mem = 0.0f;
        for (int t = 0; t < T_; ++t) {
            float m = fadd(fmul(0.95f, mem), icur[t * CURS + tid]);
            float sp = (fsub(m, 1.0f) > 0.0f) ? 1.0f : 0.0f;
            mem = fsub(m, sp);
            icur[t * CURS + tid] = sp;
        }
    }
    __syncthreads();

    // ---- AC currents: 1240 chains, float4 + fmaf
    for (int idx = tid; idx < T_ * OUT_; idx += TB_) {
        int t = idx / 10, o = idx - t * 10;
        const float* wr = sWac + o * 52;
        const float* sb = icur + t * CURS;
        float acc = 0.0f;
#pragma unroll
        for (int g4 = 0; g4 < 12; ++g4) {
            const float4 s4 = *(const float4*)(sb + (g4 << 2));
            const float4 w4 = *(const float4*)(wr + (g4 << 2));
            acc = fmaf(s4.x, w4.x, acc);
            acc = fmaf(s4.y, w4.y, acc);
            acc = fmaf(s4.z, w4.z, acc);
            acc = fmaf(s4.w, w4.w, acc);
        }
        acc = fmaf(sb[48], wr[48], acc);
        acc = fmaf(sb[49], wr[49], acc);
        acur[t * 12 + o] = acc;
    }
    __syncthreads();

    // ---- AC membrane chains + output stores
    if (tid < OUT_) {
        float mem = 0.0f;
        for (int t = 0; t < T_; ++t) {
            float m = fadd(fmul(0.95f, mem), acur[t * 12 + tid]);
            float sp = (fsub(m, 1.0f) > 0.0f) ? 1.0f : 0.0f;
            float mo = fsub(m, sp);
            mem = mo;
            size_t base = ((size_t)b * T_ + t) * OUT_ + tid;
            out[base] = sp;
            out[(size_t)(B_ * T_ * OUT_) + base] = mo;
        }
    }
}

// ---------------------------------------------------------------------------
extern "C" void kernel_launch(void* const* d_in, const int* in_sizes, int n_in,
                              void* d_out, int out_size, void* d_ws, size_t ws_size,
                              hipStream_t stream) {
    (void)in_sizes; (void)n_in; (void)out_size; (void)ws_size;
    const float* audio = (const float*)d_in[0];
    const float* gt    = (const float*)d_in[1];
    const float* Wb    = (const float*)d_in[2];
    const float* Wic   = (const float*)d_in[3];
    const float* Wac   = (const float*)d_in[4];

    float* Sg = (float*)d_ws;   // needs 256*32*125*4 = 4,096,000 B of ws

    convA<<<dim3(B_, 16), dim3(256), 0, stream>>>(audio, gt, Sg);
    snnB<<<dim3(B_), dim3(TB_), 0, stream>>>(Sg, Wb, Wic, Wac, (float*)d_out);
}

// Round 4
// 309.094 us; speedup vs baseline: 1.6557x; 1.0545x over previous
//
#include <hip/hip_runtime.h>

// Problem dims
#define B_   256
#define N_   16000
#define C_   32
#define K_   64
#define T_   124
#define NJ   125      // 128-sample half-window block sums, j = 0..124
#define HID_ 50
#define OUT_ 10
#define TB_  1024     // snnB block size
#define CURS 52       // padded stride for cur/icur (float4-aligned)

typedef unsigned int u32;
typedef float v2f __attribute__((ext_vector_type(2)));
struct __align__(16) f2x2 { v2f lo, hi; };

// Exact single f32 ops (prevent fma contraction / reassociation).
__device__ __forceinline__ float fadd(float a, float b) { return __fadd_rn(a, b); }
__device__ __forceinline__ float fmul(float a, float b) { return __fmul_rn(a, b); }
__device__ __forceinline__ float fsub(float a, float b) { return __fsub_rn(a, b); }

// Packed f32 FMA: y.lo += a.lo*tap, y.hi += a.hi*tap, tap = slot k of pair-pair T,
// broadcast via VOP3P op_sel. T lives in SGPRs (s_load'd, wave-uniform): VOP3P
// permits one SGPR source. Each half is an IEEE f32 FMA == fmaf: bit-identical.
__device__ __forceinline__ void PKFMA(v2f& y, v2f a, const f2x2& T, int k) {
    switch (k) {
    case 0:  asm("v_pk_fma_f32 %0, %1, %2, %0 op_sel:[0,0,0] op_sel_hi:[1,0,1]"
                 : "+v"(y) : "v"(a), "s"(T.lo)); break;
    case 1:  asm("v_pk_fma_f32 %0, %1, %2, %0 op_sel:[0,1,0] op_sel_hi:[1,1,1]"
                 : "+v"(y) : "v"(a), "s"(T.lo)); break;
    case 2:  asm("v_pk_fma_f32 %0, %1, %2, %0 op_sel:[0,0,0] op_sel_hi:[1,0,1]"
                 : "+v"(y) : "v"(a), "s"(T.hi)); break;
    default: asm("v_pk_fma_f32 %0, %1, %2, %0 op_sel:[0,1,0] op_sel_hi:[1,1,1]"
                 : "+v"(y) : "v"(a), "s"(T.hi)); break;
    }
}

// ---------------------------------------------------------------------------
// Kernel A: conv (SAME pad_lo=31, correlation, sequential-k f32 FMA) + relu +
// numpy-pairwise 128-block sums -> Sg[b][c][j].
//
// ROUND-18: r17's launch_bounds(256,6) VGPR cap (=> VGPR_Count 40) spilled
// the Y accumulators: WRITE_SIZE 4.26 -> 59.6 MB of scratch, kernel became
// spill-HBM-bound. Revert to (256,4) (r16 measured 64 VGPR spill-free with
// MORE live state). Keep SGPR taps (kLDS gone, 4 ds_read/q).
// Bank-conflict fix: epilogue ybuf re-padded so ch-stride=272 (==16 mod 32)
// and blk-offset=136 (==8 mod 32): each 32-lane phase of the reduce reads
// and the b128 writes hits all 32 banks once (was 2-4-way: 13.1M cy ~= 11%).
// Per-output accumulation order (q asc, e asc) unchanged: bit-exact.
// ---------------------------------------------------------------------------
__global__ __launch_bounds__(256, 4) void convA(const float* __restrict__ audio,
                                                const float* __restrict__ gt,
                                                float* __restrict__ Sg) {
    __shared__ __align__(16) float abI[1280];         //  5,120 B  [P][640] interleaved
    __shared__ __align__(16) float ybuf[4][4][272];   // 17,408 B [wave][ch][2blk*136]

    const int b = blockIdx.x, g = blockIdx.y;
    const int tid = threadIdx.x, w = tid >> 6, lane = tid & 63;
    const float* arow = audio + (size_t)b * N_;

    const int origin = (g << 10) - 32;
    // Interleaved staging: logical j = 2*i + h  <->  sample origin + P*512 + h*256 + i
    for (int idx = tid; idx < 1280; idx += 256) {
        int P = idx / 640, j = idx - P * 640;
        int ii = j >> 1, h = j & 1;
        int gi = origin + (P << 9) + (h << 8) + ii;
        float v = (gi >= 0 && gi < N_) ? arow[gi] : 0.0f;
        abI[P * 640 + (j ^ (((j >> 5) & 1) << 2))] = v;
    }
    __syncthreads();

    for (int G = 0; G < 2; ++G) {
        // wave-uniform tap row base -> scalar loads
        const int rowbase = __builtin_amdgcn_readfirstlane(((w << 3) + (G << 2)) << 6);
        const float* kg = gt + rowbase;

        v2f Y[2][4][4];   // [P][ch][d]; lo = pp=2P, hi = pp=2P+1
#pragma unroll
        for (int P = 0; P < 2; ++P)
#pragma unroll
            for (int ch = 0; ch < 4; ++ch)
#pragma unroll
                for (int d = 0; d < 4; ++d) { Y[P][ch][d].x = 0.0f; Y[P][ch][d].y = 0.0f; }

        // ---- q = 0 peel: k = e-1-d, only k>=0 terms (all from Tc)
        {
            f2x2 Tc[4];
#pragma unroll
            for (int ch = 0; ch < 4; ++ch)
                Tc[ch] = *(const f2x2*)(kg + (ch << 6));
            const int u = lane;
            const int p1 = (u << 3) ^ (((u >> 2) & 1) << 2);
#pragma unroll
            for (int P = 0; P < 2; ++P) {
                const float* abP = abI + P * 640;
                const f2x2 A0 = *(const f2x2*)(abP + p1);
                const f2x2 A1 = *(const f2x2*)(abP + (p1 ^ 4));
#pragma unroll
                for (int e = 0; e < 4; ++e) {
                    const v2f a = (e == 0) ? A0.lo : (e == 1) ? A0.hi
                                : (e == 2) ? A1.lo : A1.hi;
#pragma unroll
                    for (int ch = 0; ch < 4; ++ch)
#pragma unroll
                        for (int d = 0; d < 4; ++d) {
                            const int kb = e - 1 - d;          // compile-time
                            if (kb >= 0) PKFMA(Y[P][ch][d], a, Tc[ch], kb);
                        }
                }
            }
        }

        // ---- q = 1..15: boundary-free, NOT unrolled (live set = 1 iter)
#pragma unroll 1
        for (int q = 1; q < 16; ++q) {
            f2x2 Tm[4], Tc[4];   // taps 4(q-1)+{0..3} and 4q+{0..3} (SGPR)
#pragma unroll
            for (int ch = 0; ch < 4; ++ch) {
                Tm[ch] = *(const f2x2*)(kg + (ch << 6) + ((q - 1) << 2));
                Tc[ch] = *(const f2x2*)(kg + (ch << 6) + (q << 2));
            }
            const int u = lane + q;
            const int p1 = (u << 3) ^ (((u >> 2) & 1) << 2);
#pragma unroll
            for (int P = 0; P < 2; ++P) {
                const float* abP = abI + P * 640;
                const f2x2 A0 = *(const f2x2*)(abP + p1);
                const f2x2 A1 = *(const f2x2*)(abP + (p1 ^ 4));
#pragma unroll
                for (int e = 0; e < 4; ++e) {
                    const v2f a = (e == 0) ? A0.lo : (e == 1) ? A0.hi
                                : (e == 2) ? A1.lo : A1.hi;
#pragma unroll
                    for (int ch = 0; ch < 4; ++ch)
#pragma unroll
                        for (int d = 0; d < 4; ++d) {
                            const int ts = e - 1 - d;          // compile-time
                            if (ts >= 0) PKFMA(Y[P][ch][d], a, Tc[ch], ts);
                            else         PKFMA(Y[P][ch][d], a, Tm[ch], 4 + ts);
                        }
                }
            }
        }

        // ---- q = 16 peel: only ts<0 terms (taps 60..63)
        {
            f2x2 Tm[4];
#pragma unroll
            for (int ch = 0; ch < 4; ++ch)
                Tm[ch] = *(const f2x2*)(kg + (ch << 6) + 60);
            const int u = lane + 16;
            const int p1 = (u << 3) ^ (((u >> 2) & 1) << 2);
#pragma unroll
            for (int P = 0; P < 2; ++P) {
                const float* abP = abI + P * 640;
                const f2x2 A0 = *(const f2x2*)(abP + p1);
                const f2x2 A1 = *(const f2x2*)(abP + (p1 ^ 4));
#pragma unroll
                for (int e = 0; e < 4; ++e) {
                    const v2f a = (e == 0) ? A0.lo : (e == 1) ? A0.hi
                                : (e == 2) ? A1.lo : A1.hi;
#pragma unroll
                    for (int ch = 0; ch < 4; ++ch)
#pragma unroll
                        for (int d = 0; d < 4; ++d) {
                            const int ts = e - 1 - d;          // compile-time
                            if (ts < 0) PKFMA(Y[P][ch][d], a, Tm[ch], 4 + ts);
                        }
                }
            }
        }

        // ---- epilogue per pp (identical math/order; new conflict-free layout)
#pragma unroll
        for (int pp = 0; pp < 4; ++pp) {
            const int P = pp >> 1, h = pp & 1;
#pragma unroll
            for (int ch = 0; ch < 4; ++ch) {
                float4 z;
                z.x = fmaxf(h ? Y[P][ch][0].y : Y[P][ch][0].x, 0.0f);
                z.y = fmaxf(h ? Y[P][ch][1].y : Y[P][ch][1].x, 0.0f);
                z.z = fmaxf(h ? Y[P][ch][2].y : Y[P][ch][2].x, 0.0f);
                z.w = fmaxf(h ? Y[P][ch][3].y : Y[P][ch][3].x, 0.0f);
                *(float4*)(&ybuf[w][ch][((lane >> 5) * 136) + ((lane & 31) << 2)]) = z;
            }
            // numpy pairwise-128: 64 lanes = 4ch x 2blk x 8slots.
            {
                const int ch2 = lane >> 4, blk = (lane >> 3) & 1, j = lane & 7;
                const float* yb = &ybuf[w][ch2][blk * 136 + j];
                float r = yb[0];
#pragma unroll
                for (int m = 1; m < 16; ++m) r = fadd(r, yb[m << 3]);
                float v = fadd(r, __shfl_xor(r, 1));
                v = fadd(v, __shfl_xor(v, 2));
                v = fadd(v, __shfl_xor(v, 4));
                const int jg = (g << 3) + (pp << 1) + blk;
                const int c = (w << 3) + (G << 2) + ch2;
                if (j == 0 && jg < NJ) Sg[((size_t)b * C_ + c) * NJ + jg] = v;
            }
        }
    }
}

// ---------------------------------------------------------------------------
// Kernel B: SNN. ROUND-18:
//  - membrane phases: batch-8 prefetch of currents (8 independent ds_reads
//    issued together, then the serial chain in registers) -> amortizes the
//    ~120cy LDS latency 8x. Reads of a batch precede that thread's writes;
//    each thread owns its column: race-free, order unchanged.
//  - IC currents: output-pair (h, h+25) per thread: spike-vector float4
//    reads shared -> 39 LDS reads per 2 outputs (was 52).
//  - AC currents: same with (o, o+5).
// Per-output accumulation orders everywhere unchanged: bit-exact.
// ---------------------------------------------------------------------------
__global__ __launch_bounds__(TB_, 1) void snnB(const float* __restrict__ Sg,
                                               const float* __restrict__ Wb,
                                               const float* __restrict__ Wic,
                                               const float* __restrict__ Wac,
                                               float* __restrict__ out) {
    __shared__ float sWb[HID_ * 321];                 // 64,200 B (321%32==1)
    __shared__ __align__(16) float sWic[HID_ * 52];   // 10,400 B
    __shared__ __align__(16) float sWac[OUT_ * 52];   //  2,080 B
    __shared__ u32   mask[128 * 10];                  //  5,120 B (rows 124..127 zero)
    __shared__ __align__(16) float cur[T_ * CURS];    // 25,792 B
    __shared__ __align__(16) float icur[T_ * CURS];   // 25,792 B
    __shared__ float acur[T_ * 12];                   //  5,952 B   (total ~139.3 KB)

    const int b = blockIdx.x, tid = threadIdx.x;

    for (int i = tid; i < HID_ * 320; i += TB_) {
        int r = i / 320;
        sWb[r * 321 + (i - r * 320)] = Wb[i];
    }
    for (int i = tid; i < HID_ * HID_; i += TB_) {
        int r = i / 50;
        sWic[r * 52 + (i - r * 50)] = Wic[i];
    }
    for (int i = tid; i < OUT_ * HID_; i += TB_) {
        int r = i / 50;
        sWac[r * 52 + (i - r * 50)] = Wac[i];
    }

    // ---- AN spike bitmasks: word (t, wd) covers i in [32wd, 32wd+32)
    const float* Sb = Sg + (size_t)b * C_ * NJ;
    for (int idx = tid; idx < 1280; idx += TB_) {
        if (idx >= T_ * 10) { mask[idx] = 0; continue; }
        int t = idx / 10, wd = idx - t * 10;
        u32 m = 0;
        int c_prev = -1;
        float env = 0.0f;
        for (int k = 0; k < 32; ++k) {
            int i = wd * 32 + k;
            int c = i / 10, s = i - c * 10;
            if (c != c_prev) {
                env = fmul(fadd(Sb[c * NJ + t], Sb[c * NJ + t + 1]), 0.00390625f);
                c_prev = c;
            }
            float sf = (s == 9) ? 1.5f : (float)(0.5 + (double)s * (1.0 / 9.0));
            if (fsub(fmul(env, sf), 0.5f) > 0.0f) m |= (1u << k);
        }
        mask[idx] = m;
    }
    __syncthreads();

    // ---- Bushy currents: 8 t-chains per weight-row pass (t = t0 + 16m)
    if (tid < 16 * HID_) {
        const int t0 = tid / 50, h = tid - t0 * 50;
        const float* wr = sWb + h * 321;
        const u32* mrow = mask + t0 * 10;
        float a0 = 0.0f, a1 = 0.0f, a2 = 0.0f, a3 = 0.0f;
        float a4 = 0.0f, a5 = 0.0f, a6 = 0.0f, a7 = 0.0f;
#pragma unroll 1
        for (int wi = 0; wi < 10; ++wi) {
            const u32 w0 = mrow[wi], w1 = mrow[160 + wi];
            const u32 w2 = mrow[320 + wi], w3 = mrow[480 + wi];
            const u32 w4 = mrow[640 + wi], w5 = mrow[800 + wi];
            const u32 w6 = mrow[960 + wi], w7 = mrow[1120 + wi];
#pragma unroll
            for (int b2 = 0; b2 < 32; ++b2) {
                const float wv = wr[(wi << 5) + b2];
                const int iw = __float_as_int(wv);
                a0 = fadd(a0, __int_as_float(iw & __builtin_amdgcn_sbfe((int)w0, b2, 1)));
                a1 = fadd(a1, __int_as_float(iw & __builtin_amdgcn_sbfe((int)w1, b2, 1)));
                a2 = fadd(a2, __int_as_float(iw & __builtin_amdgcn_sbfe((int)w2, b2, 1)));
                a3 = fadd(a3, __int_as_float(iw & __builtin_amdgcn_sbfe((int)w3, b2, 1)));
                a4 = fadd(a4, __int_as_float(iw & __builtin_amdgcn_sbfe((int)w4, b2, 1)));
                a5 = fadd(a5, __int_as_float(iw & __builtin_amdgcn_sbfe((int)w5, b2, 1)));
                a6 = fadd(a6, __int_as_float(iw & __builtin_amdgcn_sbfe((int)w6, b2, 1)));
                a7 = fadd(a7, __int_as_float(iw & __builtin_amdgcn_sbfe((int)w7, b2, 1)));
            }
        }
        cur[(t0      ) * CURS + h] = a0;
        cur[(t0 + 16 ) * CURS + h] = a1;
        cur[(t0 + 32 ) * CURS + h] = a2;
        cur[(t0 + 48 ) * CURS + h] = a3;
        cur[(t0 + 64 ) * CURS + h] = a4;
        cur[(t0 + 80 ) * CURS + h] = a5;
        cur[(t0 + 96 ) * CURS + h] = a6;
        if (t0 + 112 < T_) cur[(t0 + 112) * CURS + h] = a7;
    }
    __syncthreads();

    // ---- Bushy membrane chains: batch-8 prefetch, serial chain in regs
    if (tid < HID_) {
        float mem = 0.0f;
        for (int t0 = 0; t0 < 120; t0 += 8) {
            float c0[8];
#pragma unroll
            for (int k = 0; k < 8; ++k) c0[k] = cur[(t0 + k) * CURS + tid];
#pragma unroll
            for (int k = 0; k < 8; ++k) {
                float m = fadd(fmul(0.95f, mem), c0[k]);
                float sp = (fsub(m, 1.0f) > 0.0f) ? 1.0f : 0.0f;
                mem = fsub(m, sp);
                cur[(t0 + k) * CURS + tid] = sp;
            }
        }
        for (int t = 120; t < T_; ++t) {
            float m = fadd(fmul(0.95f, mem), cur[t * CURS + tid]);
            float sp = (fsub(m, 1.0f) > 0.0f) ? 1.0f : 0.0f;
            mem = fsub(m, sp);
            cur[t * CURS + tid] = sp;
        }
    }
    __syncthreads();

    // ---- IC currents: output-pair (h, h+25): spike reads shared
    for (int idx = tid; idx < T_ * 25; idx += TB_) {
        int t = idx / 25, hp = idx - t * 25;
        const float* w0 = sWic + hp * 52;
        const float* w1 = sWic + (hp + 25) * 52;
        const float* sb = cur + t * CURS;
        float acc0 = 0.0f, acc1 = 0.0f;
#pragma unroll
        for (int g4 = 0; g4 < 12; ++g4) {
            const float4 s4 = *(const float4*)(sb + (g4 << 2));
            const float4 wa = *(const float4*)(w0 + (g4 << 2));
            const float4 wb = *(const float4*)(w1 + (g4 << 2));
            acc0 = fmaf(s4.x, wa.x, acc0);  acc1 = fmaf(s4.x, wb.x, acc1);
            acc0 = fmaf(s4.y, wa.y, acc0);  acc1 = fmaf(s4.y, wb.y, acc1);
            acc0 = fmaf(s4.z, wa.z, acc0);  acc1 = fmaf(s4.z, wb.z, acc1);
            acc0 = fmaf(s4.w, wa.w, acc0);  acc1 = fmaf(s4.w, wb.w, acc1);
        }
        acc0 = fmaf(sb[48], w0[48], acc0);  acc1 = fmaf(sb[48], w1[48], acc1);
        acc0 = fmaf(sb[49], w0[49], acc0);  acc1 = fmaf(sb[49], w1[49], acc1);
        icur[t * CURS + hp] = acc0;
        icur[t * CURS + hp + 25] = acc1;
    }
    __syncthreads();

    // ---- IC membrane chains: batch-8
    if (tid < HID_) {
        float mem = 0.0f;
        for (int t0 = 0; t0 < 120; t0 += 8) {
            float c0[8];
#pragma unroll
            for (int k = 0; k < 8; ++k) c0[k] = icur[(t0 + k) * CURS + tid];
#pragma unroll
            for (int k = 0; k < 8; ++k) {
                float m = fadd(fmul(0.95f, mem), c0[k]);
                float sp = (fsub(m, 1.0f) > 0.0f) ? 1.0f : 0.0f;
                mem = fsub(m, sp);
                icur[(t0 + k) * CURS + tid] = sp;
            }
        }
        for (int t = 120; t < T_; ++t) {
            float m = fadd(fmul(0.95f, mem), icur[t * CURS + tid]);
            float sp = (fsub(m, 1.0f) > 0.0f) ? 1.0f : 0.0f;
            mem = fsub(m, sp);
            icur[t * CURS + tid] = sp;
        }
    }
    __syncthreads();

    // ---- AC currents: output-pair (o, o+5): spike reads shared
    for (int idx = tid; idx < T_ * 5; idx += TB_) {
        int t = idx / 5, op = idx - t * 5;
        const float* w0 = sWac + op * 52;
        const float* w1 = sWac + (op + 5) * 52;
        const float* sb = icur + t * CURS;
        float acc0 = 0.0f, acc1 = 0.0f;
#pragma unroll
        for (int g4 = 0; g4 < 12; ++g4) {
            const float4 s4 = *(const float4*)(sb + (g4 << 2));
            const float4 wa = *(const float4*)(w0 + (g4 << 2));
            const float4 wb = *(const float4*)(w1 + (g4 << 2));
            acc0 = fmaf(s4.x, wa.x, acc0);  acc1 = fmaf(s4.x, wb.x, acc1);
            acc0 = fmaf(s4.y, wa.y, acc0);  acc1 = fmaf(s4.y, wb.y, acc1);
            acc0 = fmaf(s4.z, wa.z, acc0);  acc1 = fmaf(s4.z, wb.z, acc1);
            acc0 = fmaf(s4.w, wa.w, acc0);  acc1 = fmaf(s4.w, wb.w, acc1);
        }
        acc0 = fmaf(sb[48], w0[48], acc0);  acc1 = fmaf(sb[48], w1[48], acc1);
        acc0 = fmaf(sb[49], w0[49], acc0);  acc1 = fmaf(sb[49], w1[49], acc1);
        acur[t * 12 + op] = acc0;
        acur[t * 12 + op + 5] = acc1;
    }
    __syncthreads();

    // ---- AC membrane chains + output stores: batch-8
    if (tid < OUT_) {
        float mem = 0.0f;
        for (int t0 = 0; t0 < 120; t0 += 8) {
            float c0[8];
#pragma unroll
            for (int k = 0; k < 8; ++k) c0[k] = acur[(t0 + k) * 12 + tid];
#pragma unroll
            for (int k = 0; k < 8; ++k) {
                float m = fadd(fmul(0.95f, mem), c0[k]);
                float sp = (fsub(m, 1.0f) > 0.0f) ? 1.0f : 0.0f;
                float mo = fsub(m, sp);
                mem = mo;
                size_t base = ((size_t)b * T_ + (t0 + k)) * OUT_ + tid;
                out[base] = sp;
                out[(size_t)(B_ * T_ * OUT_) + base] = mo;
            }
        }
        for (int t = 120; t < T_; ++t) {
            float m = fadd(fmul(0.95f, mem), acur[t * 12 + tid]);
            float sp = (fsub(m, 1.0f) > 0.0f) ? 1.0f : 0.0f;
            float mo = fsub(m, sp);
            mem = mo;
            size_t base = ((size_t)b * T_ + t) * OUT_ + tid;
            out[base] = sp;
            out[(size_t)(B_ * T_ * OUT_) + base] = mo;
        }
    }
}

// ---------------------------------------------------------------------------
extern "C" void kernel_launch(void* const* d_in, const int* in_sizes, int n_in,
                              void* d_out, int out_size, void* d_ws, size_t ws_size,
                              hipStream_t stream) {
    (void)in_sizes; (void)n_in; (void)out_size; (void)ws_size;
    const float* audio = (const float*)d_in[0];
    const float* gt    = (const float*)d_in[1];
    const float* Wb    = (const float*)d_in[2];
    const float* Wic   = (const float*)d_in[3];
    const float* Wac   = (const float*)d_in[4];

    float* Sg = (float*)d_ws;   // needs 256*32*125*4 = 4,096,000 B of ws

    convA<<<dim3(B_, 16), dim3(256), 0, stream>>>(audio, gt, Sg);
    snnB<<<dim3(B_), dim3(TB_), 0, stream>>>(Sg, Wb, Wic, Wac, (float*)d_out);
}

// Round 5
// 308.360 us; speedup vs baseline: 1.6597x; 1.0024x over previous
//
#include <hip/hip_runtime.h>

// Problem dims
#define B_   256
#define N_   16000
#define C_   32
#define K_   64
#define T_   124
#define NJ   125      // 128-sample half-window block sums, j = 0..124
#define HID_ 50
#define OUT_ 10
#define TB_  1024     // snnB block size
#define CURS 52       // padded stride for cur/icur (float4-aligned)

typedef unsigned int u32;
typedef float v2f __attribute__((ext_vector_type(2)));
struct __align__(16) f2x2 { v2f lo, hi; };

// Exact single f32 ops (prevent fma contraction / reassociation).
__device__ __forceinline__ float fadd(float a, float b) { return __fadd_rn(a, b); }
__device__ __forceinline__ float fmul(float a, float b) { return __fmul_rn(a, b); }
__device__ __forceinline__ float fsub(float a, float b) { return __fsub_rn(a, b); }

// Packed f32 FMA: y.lo += a.lo*tap, y.hi += a.hi*tap, tap = slot k of pair-pair T,
// broadcast via VOP3P op_sel. T lives in SGPRs (s_load'd, wave-uniform): VOP3P
// permits one SGPR source. Each half is an IEEE f32 FMA == fmaf: bit-identical.
__device__ __forceinline__ void PKFMA(v2f& y, v2f a, const f2x2& T, int k) {
    switch (k) {
    case 0:  asm("v_pk_fma_f32 %0, %1, %2, %0 op_sel:[0,0,0] op_sel_hi:[1,0,1]"
                 : "+v"(y) : "v"(a), "s"(T.lo)); break;
    case 1:  asm("v_pk_fma_f32 %0, %1, %2, %0 op_sel:[0,1,0] op_sel_hi:[1,1,1]"
                 : "+v"(y) : "v"(a), "s"(T.lo)); break;
    case 2:  asm("v_pk_fma_f32 %0, %1, %2, %0 op_sel:[0,0,0] op_sel_hi:[1,0,1]"
                 : "+v"(y) : "v"(a), "s"(T.hi)); break;
    default: asm("v_pk_fma_f32 %0, %1, %2, %0 op_sel:[0,1,0] op_sel_hi:[1,1,1]"
                 : "+v"(y) : "v"(a), "s"(T.hi)); break;
    }
}

// ---------------------------------------------------------------------------
// Kernel A: conv (SAME pad_lo=31, correlation, sequential-k f32 FMA) + relu +
// numpy-pairwise 128-block sums -> Sg[b][c][j].
//
// ROUND-19: occupancy was the limiter (40% = ~3 waves/SIMD; per-q s_load/
// ds_read latency exposed). Halve the per-pass tile: Y[1][4][4] (32 acc
// VGPRs), 4 passes over (P,G) instead of 2 over G. Live set ~56 VGPRs ->
// launch_bounds(256,6) (cap 85: 30-reg headroom, no r3-style spill) -> 6
// waves/SIMD. pk_fma total unchanged (4096/thread); per-output accumulation
// order (q asc, e asc) unchanged: bit-exact.
// ---------------------------------------------------------------------------
__global__ __launch_bounds__(256, 6) void convA(const float* __restrict__ audio,
                                                const float* __restrict__ gt,
                                                float* __restrict__ Sg) {
    __shared__ __align__(16) float abI[1280];         //  5,120 B  [P][640] interleaved
    __shared__ __align__(16) float ybuf[4][4][272];   // 17,408 B [wave][ch][2blk*136]

    const int b = blockIdx.x, g = blockIdx.y;
    const int tid = threadIdx.x, w = tid >> 6, lane = tid & 63;
    const float* arow = audio + (size_t)b * N_;

    const int origin = (g << 10) - 32;
    // Interleaved staging: logical j = 2*i + h  <->  sample origin + P*512 + h*256 + i
    for (int idx = tid; idx < 1280; idx += 256) {
        int P = idx / 640, j = idx - P * 640;
        int ii = j >> 1, h = j & 1;
        int gi = origin + (P << 9) + (h << 8) + ii;
        float v = (gi >= 0 && gi < N_) ? arow[gi] : 0.0f;
        abI[P * 640 + (j ^ (((j >> 5) & 1) << 2))] = v;
    }
    __syncthreads();

#pragma unroll 1
    for (int P = 0; P < 2; ++P) {
        const float* abP = abI + P * 640;
#pragma unroll 1
        for (int G = 0; G < 2; ++G) {
            // wave-uniform tap row base -> scalar loads
            const int rowbase = __builtin_amdgcn_readfirstlane(((w << 3) + (G << 2)) << 6);
            const float* kg = gt + rowbase;

            v2f Y[4][4];   // [ch][d]; lo = pp=2P, hi = pp=2P+1
#pragma unroll
            for (int ch = 0; ch < 4; ++ch)
#pragma unroll
                for (int d = 0; d < 4; ++d) { Y[ch][d].x = 0.0f; Y[ch][d].y = 0.0f; }

            // ---- q = 0 peel: k = e-1-d, only k>=0 terms (all from Tc)
            {
                f2x2 Tc[4];
#pragma unroll
                for (int ch = 0; ch < 4; ++ch)
                    Tc[ch] = *(const f2x2*)(kg + (ch << 6));
                const int u = lane;
                const int p1 = (u << 3) ^ (((u >> 2) & 1) << 2);
                const f2x2 A0 = *(const f2x2*)(abP + p1);
                const f2x2 A1 = *(const f2x2*)(abP + (p1 ^ 4));
#pragma unroll
                for (int e = 0; e < 4; ++e) {
                    const v2f a = (e == 0) ? A0.lo : (e == 1) ? A0.hi
                                : (e == 2) ? A1.lo : A1.hi;
#pragma unroll
                    for (int ch = 0; ch < 4; ++ch)
#pragma unroll
                        for (int d = 0; d < 4; ++d) {
                            const int kb = e - 1 - d;          // compile-time
                            if (kb >= 0) PKFMA(Y[ch][d], a, Tc[ch], kb);
                        }
                }
            }

            // ---- q = 1..15: boundary-free, NOT unrolled (live set = 1 iter)
#pragma unroll 1
            for (int q = 1; q < 16; ++q) {
                f2x2 Tm[4], Tc[4];   // taps 4(q-1)+{0..3} and 4q+{0..3} (SGPR)
#pragma unroll
                for (int ch = 0; ch < 4; ++ch) {
                    Tm[ch] = *(const f2x2*)(kg + (ch << 6) + ((q - 1) << 2));
                    Tc[ch] = *(const f2x2*)(kg + (ch << 6) + (q << 2));
                }
                const int u = lane + q;
                const int p1 = (u << 3) ^ (((u >> 2) & 1) << 2);
                const f2x2 A0 = *(const f2x2*)(abP + p1);
                const f2x2 A1 = *(const f2x2*)(abP + (p1 ^ 4));
#pragma unroll
                for (int e = 0; e < 4; ++e) {
                    const v2f a = (e == 0) ? A0.lo : (e == 1) ? A0.hi
                                : (e == 2) ? A1.lo : A1.hi;
#pragma unroll
                    for (int ch = 0; ch < 4; ++ch)
#pragma unroll
                        for (int d = 0; d < 4; ++d) {
                            const int ts = e - 1 - d;          // compile-time
                            if (ts >= 0) PKFMA(Y[ch][d], a, Tc[ch], ts);
                            else         PKFMA(Y[ch][d], a, Tm[ch], 4 + ts);
                        }
                }
            }

            // ---- q = 16 peel: only ts<0 terms (taps 60..63)
            {
                f2x2 Tm[4];
#pragma unroll
                for (int ch = 0; ch < 4; ++ch)
                    Tm[ch] = *(const f2x2*)(kg + (ch << 6) + 60);
                const int u = lane + 16;
                const int p1 = (u << 3) ^ (((u >> 2) & 1) << 2);
                const f2x2 A0 = *(const f2x2*)(abP + p1);
                const f2x2 A1 = *(const f2x2*)(abP + (p1 ^ 4));
#pragma unroll
                for (int e = 0; e < 4; ++e) {
                    const v2f a = (e == 0) ? A0.lo : (e == 1) ? A0.hi
                                : (e == 2) ? A1.lo : A1.hi;
#pragma unroll
                    for (int ch = 0; ch < 4; ++ch)
#pragma unroll
                        for (int d = 0; d < 4; ++d) {
                            const int ts = e - 1 - d;          // compile-time
                            if (ts < 0) PKFMA(Y[ch][d], a, Tm[ch], 4 + ts);
                        }
                }
            }

            // ---- epilogue for pp = 2P+h (identical math/order)
#pragma unroll
            for (int h = 0; h < 2; ++h) {
                const int pp = (P << 1) + h;
#pragma unroll
                for (int ch = 0; ch < 4; ++ch) {
                    float4 z;
                    z.x = fmaxf(h ? Y[ch][0].y : Y[ch][0].x, 0.0f);
                    z.y = fmaxf(h ? Y[ch][1].y : Y[ch][1].x, 0.0f);
                    z.z = fmaxf(h ? Y[ch][2].y : Y[ch][2].x, 0.0f);
                    z.w = fmaxf(h ? Y[ch][3].y : Y[ch][3].x, 0.0f);
                    *(float4*)(&ybuf[w][ch][((lane >> 5) * 136) + ((lane & 31) << 2)]) = z;
                }
                // numpy pairwise-128: 64 lanes = 4ch x 2blk x 8slots.
                {
                    const int ch2 = lane >> 4, blk = (lane >> 3) & 1, j = lane & 7;
                    const float* yb = &ybuf[w][ch2][blk * 136 + j];
                    float r = yb[0];
#pragma unroll
                    for (int m = 1; m < 16; ++m) r = fadd(r, yb[m << 3]);
                    float v = fadd(r, __shfl_xor(r, 1));
                    v = fadd(v, __shfl_xor(v, 2));
                    v = fadd(v, __shfl_xor(v, 4));
                    const int jg = (g << 3) + (pp << 1) + blk;
                    const int c = (w << 3) + (G << 2) + ch2;
                    if (j == 0 && jg < NJ) Sg[((size_t)b * C_ + c) * NJ + jg] = v;
                }
            }
        }
    }
}

// ---------------------------------------------------------------------------
// Kernel B: SNN. ROUND-19: bushy currents pack chain-pairs into v2f
// accumulators: lo/hi = iw & sbfe(w_even/odd), one v_pk_add_f32 replaces two
// fadd (each half IEEE-exact, per-chain order unchanged: bit-exact).
// 3 -> 2.5 VALU per element on the dominant phase.
// ---------------------------------------------------------------------------
__global__ __launch_bounds__(TB_, 1) void snnB(const float* __restrict__ Sg,
                                               const float* __restrict__ Wb,
                                               const float* __restrict__ Wic,
                                               const float* __restrict__ Wac,
                                               float* __restrict__ out) {
    __shared__ float sWb[HID_ * 321];                 // 64,200 B (321%32==1)
    __shared__ __align__(16) float sWic[HID_ * 52];   // 10,400 B
    __shared__ __align__(16) float sWac[OUT_ * 52];   //  2,080 B
    __shared__ u32   mask[128 * 10];                  //  5,120 B (rows 124..127 zero)
    __shared__ __align__(16) float cur[T_ * CURS];    // 25,792 B
    __shared__ __align__(16) float icur[T_ * CURS];   // 25,792 B
    __shared__ float acur[T_ * 12];                   //  5,952 B   (total ~139.3 KB)

    const int b = blockIdx.x, tid = threadIdx.x;

    for (int i = tid; i < HID_ * 320; i += TB_) {
        int r = i / 320;
        sWb[r * 321 + (i - r * 320)] = Wb[i];
    }
    for (int i = tid; i < HID_ * HID_; i += TB_) {
        int r = i / 50;
        sWic[r * 52 + (i - r * 50)] = Wic[i];
    }
    for (int i = tid; i < OUT_ * HID_; i += TB_) {
        int r = i / 50;
        sWac[r * 52 + (i - r * 50)] = Wac[i];
    }

    // ---- AN spike bitmasks: word (t, wd) covers i in [32wd, 32wd+32)
    const float* Sb = Sg + (size_t)b * C_ * NJ;
    for (int idx = tid; idx < 1280; idx += TB_) {
        if (idx >= T_ * 10) { mask[idx] = 0; continue; }
        int t = idx / 10, wd = idx - t * 10;
        u32 m = 0;
        int c_prev = -1;
        float env = 0.0f;
        for (int k = 0; k < 32; ++k) {
            int i = wd * 32 + k;
            int c = i / 10, s = i - c * 10;
            if (c != c_prev) {
                env = fmul(fadd(Sb[c * NJ + t], Sb[c * NJ + t + 1]), 0.00390625f);
                c_prev = c;
            }
            float sf = (s == 9) ? 1.5f : (float)(0.5 + (double)s * (1.0 / 9.0));
            if (fsub(fmul(env, sf), 0.5f) > 0.0f) m |= (1u << k);
        }
        mask[idx] = m;
    }
    __syncthreads();

    // ---- Bushy currents: 8 t-chains per weight-row pass (t = t0 + 16m),
    //      packed as 4 v2f accumulators (v_pk_add_f32)
    if (tid < 16 * HID_) {
        const int t0 = tid / 50, h = tid - t0 * 50;
        const float* wr = sWb + h * 321;
        const u32* mrow = mask + t0 * 10;
        v2f A0v = {0.0f, 0.0f}, A1v = {0.0f, 0.0f};
        v2f A2v = {0.0f, 0.0f}, A3v = {0.0f, 0.0f};
#pragma unroll 1
        for (int wi = 0; wi < 10; ++wi) {
            const u32 w0 = mrow[wi], w1 = mrow[160 + wi];
            const u32 w2 = mrow[320 + wi], w3 = mrow[480 + wi];
            const u32 w4 = mrow[640 + wi], w5 = mrow[800 + wi];
            const u32 w6 = mrow[960 + wi], w7 = mrow[1120 + wi];
#pragma unroll
            for (int b2 = 0; b2 < 32; ++b2) {
                const float wv = wr[(wi << 5) + b2];
                const int iw = __float_as_int(wv);
                v2f p0, p1, p2, p3;
                p0.x = __int_as_float(iw & __builtin_amdgcn_sbfe((int)w0, b2, 1));
                p0.y = __int_as_float(iw & __builtin_amdgcn_sbfe((int)w1, b2, 1));
                p1.x = __int_as_float(iw & __builtin_amdgcn_sbfe((int)w2, b2, 1));
                p1.y = __int_as_float(iw & __builtin_amdgcn_sbfe((int)w3, b2, 1));
                p2.x = __int_as_float(iw & __builtin_amdgcn_sbfe((int)w4, b2, 1));
                p2.y = __int_as_float(iw & __builtin_amdgcn_sbfe((int)w5, b2, 1));
                p3.x = __int_as_float(iw & __builtin_amdgcn_sbfe((int)w6, b2, 1));
                p3.y = __int_as_float(iw & __builtin_amdgcn_sbfe((int)w7, b2, 1));
                A0v = A0v + p0;   // v_pk_add_f32: each half IEEE fadd
                A1v = A1v + p1;
                A2v = A2v + p2;
                A3v = A3v + p3;
            }
        }
        cur[(t0      ) * CURS + h] = A0v.x;
        cur[(t0 + 16 ) * CURS + h] = A0v.y;
        cur[(t0 + 32 ) * CURS + h] = A1v.x;
        cur[(t0 + 48 ) * CURS + h] = A1v.y;
        cur[(t0 + 64 ) * CURS + h] = A2v.x;
        cur[(t0 + 80 ) * CURS + h] = A2v.y;
        cur[(t0 + 96 ) * CURS + h] = A3v.x;
        if (t0 + 112 < T_) cur[(t0 + 112) * CURS + h] = A3v.y;
    }
    __syncthreads();

    // ---- Bushy membrane chains: batch-8 prefetch, serial chain in regs
    if (tid < HID_) {
        float mem = 0.0f;
        for (int t0 = 0; t0 < 120; t0 += 8) {
            float c0[8];
#pragma unroll
            for (int k = 0; k < 8; ++k) c0[k] = cur[(t0 + k) * CURS + tid];
#pragma unroll
            for (int k = 0; k < 8; ++k) {
                float m = fadd(fmul(0.95f, mem), c0[k]);
                float sp = (fsub(m, 1.0f) > 0.0f) ? 1.0f : 0.0f;
                mem = fsub(m, sp);
                cur[(t0 + k) * CURS + tid] = sp;
            }
        }
        for (int t = 120; t < T_; ++t) {
            float m = fadd(fmul(0.95f, mem), cur[t * CURS + tid]);
            float sp = (fsub(m, 1.0f) > 0.0f) ? 1.0f : 0.0f;
            mem = fsub(m, sp);
            cur[t * CURS + tid] = sp;
        }
    }
    __syncthreads();

    // ---- IC currents: output-pair (h, h+25): spike reads shared
    for (int idx = tid; idx < T_ * 25; idx += TB_) {
        int t = idx / 25, hp = idx - t * 25;
        const float* w0 = sWic + hp * 52;
        const float* w1 = sWic + (hp + 25) * 52;
        const float* sb = cur + t * CURS;
        float acc0 = 0.0f, acc1 = 0.0f;
#pragma unroll
        for (int g4 = 0; g4 < 12; ++g4) {
            const float4 s4 = *(const float4*)(sb + (g4 << 2));
            const float4 wa = *(const float4*)(w0 + (g4 << 2));
            const float4 wb = *(const float4*)(w1 + (g4 << 2));
            acc0 = fmaf(s4.x, wa.x, acc0);  acc1 = fmaf(s4.x, wb.x, acc1);
            acc0 = fmaf(s4.y, wa.y, acc0);  acc1 = fmaf(s4.y, wb.y, acc1);
            acc0 = fmaf(s4.z, wa.z, acc0);  acc1 = fmaf(s4.z, wb.z, acc1);
            acc0 = fmaf(s4.w, wa.w, acc0);  acc1 = fmaf(s4.w, wb.w, acc1);
        }
        acc0 = fmaf(sb[48], w0[48], acc0);  acc1 = fmaf(sb[48], w1[48], acc1);
        acc0 = fmaf(sb[49], w0[49], acc0);  acc1 = fmaf(sb[49], w1[49], acc1);
        icur[t * CURS + hp] = acc0;
        icur[t * CURS + hp + 25] = acc1;
    }
    __syncthreads();

    // ---- IC membrane chains: batch-8
    if (tid < HID_) {
        float mem = 0.0f;
        for (int t0 = 0; t0 < 120; t0 += 8) {
            float c0[8];
#pragma unroll
            for (int k = 0; k < 8; ++k) c0[k] = icur[(t0 + k) * CURS + tid];
#pragma unroll
            for (int k = 0; k < 8; ++k) {
                float m = fadd(fmul(0.95f, mem), c0[k]);
                float sp = (fsub(m, 1.0f) > 0.0f) ? 1.0f : 0.0f;
                mem = fsub(m, sp);
                icur[(t0 + k) * CURS + tid] = sp;
            }
        }
        for (int t = 120; t < T_; ++t) {
            float m = fadd(fmul(0.95f, mem), icur[t * CURS + tid]);
            float sp = (fsub(m, 1.0f) > 0.0f) ? 1.0f : 0.0f;
            mem = fsub(m, sp);
            icur[t * CURS + tid] = sp;
        }
    }
    __syncthreads();

    // ---- AC currents: output-pair (o, o+5): spike reads shared
    for (int idx = tid; idx < T_ * 5; idx += TB_) {
        int t = idx / 5, op = idx - t * 5;
        const float* w0 = sWac + op * 52;
        const float* w1 = sWac + (op + 5) * 52;
        const float* sb = icur + t * CURS;
        float acc0 = 0.0f, acc1 = 0.0f;
#pragma unroll
        for (int g4 = 0; g4 < 12; ++g4) {
            const float4 s4 = *(const float4*)(sb + (g4 << 2));
            const float4 wa = *(const float4*)(w0 + (g4 << 2));
            const float4 wb = *(const float4*)(w1 + (g4 << 2));
            acc0 = fmaf(s4.x, wa.x, acc0);  acc1 = fmaf(s4.x, wb.x, acc1);
            acc0 = fmaf(s4.y, wa.y, acc0);  acc1 = fmaf(s4.y, wb.y, acc1);
            acc0 = fmaf(s4.z, wa.z, acc0);  acc1 = fmaf(s4.z, wb.z, acc1);
            acc0 = fmaf(s4.w, wa.w, acc0);  acc1 = fmaf(s4.w, wb.w, acc1);
        }
        acc0 = fmaf(sb[48], w0[48], acc0);  acc1 = fmaf(sb[48], w1[48], acc1);
        acc0 = fmaf(sb[49], w0[49], acc0);  acc1 = fmaf(sb[49], w1[49], acc1);
        acur[t * 12 + op] = acc0;
        acur[t * 12 + op + 5] = acc1;
    }
    __syncthreads();

    // ---- AC membrane chains + output stores: batch-8
    if (tid < OUT_) {
        float mem = 0.0f;
        for (int t0 = 0; t0 < 120; t0 += 8) {
            float c0[8];
#pragma unroll
            for (int k = 0; k < 8; ++k) c0[k] = acur[(t0 + k) * 12 + tid];
#pragma unroll
            for (int k = 0; k < 8; ++k) {
                float m = fadd(fmul(0.95f, mem), c0[k]);
                float sp = (fsub(m, 1.0f) > 0.0f) ? 1.0f : 0.0f;
                float mo = fsub(m, sp);
                mem = mo;
                size_t base = ((size_t)b * T_ + (t0 + k)) * OUT_ + tid;
                out[base] = sp;
                out[(size_t)(B_ * T_ * OUT_) + base] = mo;
            }
        }
        for (int t = 120; t < T_; ++t) {
            float m = fadd(fmul(0.95f, mem), acur[t * 12 + tid]);
            float sp = (fsub(m, 1.0f) > 0.0f) ? 1.0f : 0.0f;
            float mo = fsub(m, sp);
            mem = mo;
            size_t base = ((size_t)b * T_ + t) * OUT_ + tid;
            out[base] = sp;
            out[(size_t)(B_ * T_ * OUT_) + base] = mo;
        }
    }
}

// ---------------------------------------------------------------------------
extern "C" void kernel_launch(void* const* d_in, const int* in_sizes, int n_in,
                              void* d_out, int out_size, void* d_ws, size_t ws_size,
                              hipStream_t stream) {
    (void)in_sizes; (void)n_in; (void)out_size; (void)ws_size;
    const float* audio = (const float*)d_in[0];
    const float* gt    = (const float*)d_in[1];
    const float* Wb    = (const float*)d_in[2];
    const float* Wic   = (const float*)d_in[3];
    const float* Wac   = (const float*)d_in[4];

    float* Sg = (float*)d_ws;   // needs 256*32*125*4 = 4,096,000 B of ws

    convA<<<dim3(B_, 16), dim3(256), 0, stream>>>(audio, gt, Sg);
    snnB<<<dim3(B_), dim3(TB_), 0, stream>>>(Sg, Wb, Wic, Wac, (float*)d_out);
}